// Round 5
// baseline (62.931 us; speedup 1.0000x reference)
//
#include <hip/hip_runtime.h>
#include <hip/hip_bf16.h>
#include <math.h>

#define T_DIM 32
#define B_DIM 128
#define D_DIM 512
#define M_DIM 1024

constexpr float DT = 0.1875f;            // 3.0 / 16

typedef __attribute__((ext_vector_type(8))) short bf16x8;   // 8 bf16 = 4 VGPR
typedef __attribute__((ext_vector_type(4))) float f32x4;    // MFMA acc
typedef __attribute__((ext_vector_type(2))) float f32x2;    // packed (cos,sin)

__device__ __forceinline__ ushort f2bf(float f) {           // RNE fp32->bf16
    unsigned u = __float_as_uint(f);
    u += 0x7FFFu + ((u >> 16) & 1u);
    return (ushort)(u >> 16);
}

// v_sin_f32/v_cos_f32 take input in REVOLUTIONS (ISA: D=sin(S0*2pi)); reduce with floor.
__device__ __forceinline__ void fast_sincos(float theta, float& s, float& c) {
    constexpr float INV_2PI = 0.15915494309189535f;
    float r = theta * INV_2PI;
    r -= floorf(r);
    s = __builtin_amdgcn_sinf(r);
    c = __builtin_amdgcn_cosf(r);
}

// ---------- K1: prep. blocks 0..15: A-colnorm + transpose -> ant (bf16).
//                blocks 16..1039: z fp32 -> bf16 copy. ----------
__global__ __launch_bounds__(256) void prep_kernel(const float* __restrict__ A,
                                                   const float* __restrict__ z,
                                                   ushort* __restrict__ zb,
                                                   ushort* __restrict__ ant) {
    __shared__ float tile[64][65];
    __shared__ float nrm[4][64];
    __shared__ float inv[64];

    const int bid = blockIdx.x;
    const int tid = threadIdx.x;

    if (bid >= 16) {                       // ---- zconv part ----
        const size_t i = ((size_t)(bid - 16) * 256 + tid) * 8;
        const float4 a = *reinterpret_cast<const float4*>(&z[i]);
        const float4 b = *reinterpret_cast<const float4*>(&z[i + 4]);
        uint4 p;
        p.x = (unsigned)f2bf(a.x) | ((unsigned)f2bf(a.y) << 16);
        p.y = (unsigned)f2bf(a.z) | ((unsigned)f2bf(a.w) << 16);
        p.z = (unsigned)f2bf(b.x) | ((unsigned)f2bf(b.y) << 16);
        p.w = (unsigned)f2bf(b.z) | ((unsigned)f2bf(b.w) << 16);
        *reinterpret_cast<uint4*>(&zb[i]) = p;
        return;
    }

    // ---- ant part: 64 m-columns per block ----
    const int mB   = bid * 64;
    const int mloc = tid & 63;
    const int q    = tid >> 6;             // 4 d-quarters of 128
    float ss = 0.0f;
#pragma unroll 8
    for (int i = 0; i < 128; ++i) {
        const float v = A[(size_t)(q * 128 + i) * M_DIM + mB + mloc];
        ss = fmaf(v, v, ss);
    }
    nrm[q][mloc] = ss;
    __syncthreads();
    if (tid < 64) {
        const float tot = nrm[0][tid] + nrm[1][tid] + nrm[2][tid] + nrm[3][tid];
        inv[tid] = 1.0f / fmaxf(sqrtf(tot), 1e-12f);
    }

    for (int ch = 0; ch < 8; ++ch) {       // 8 chunks of 64 d
        __syncthreads();                   // tile reuse + inv ready (first iter)
        const int dB = ch * 64;
        const int r  = tid >> 4;           // 0..15
        const int c4 = (tid & 15) * 4;
#pragma unroll
        for (int rr = 0; rr < 4; ++rr) {
            const float4 v = *reinterpret_cast<const float4*>(
                &A[(size_t)(dB + r + rr * 16) * M_DIM + mB + c4]);
            tile[r + rr * 16][c4]     = v.x;
            tile[r + rr * 16][c4 + 1] = v.y;
            tile[r + rr * 16][c4 + 2] = v.z;
            tile[r + rr * 16][c4 + 3] = v.w;
        }
        __syncthreads();
#pragma unroll
        for (int it = 0; it < 2; ++it) {
            const int ci = it * 256 + tid;
            const int m  = ci >> 3;        // 0..63
            const int d8 = (ci & 7) * 8;   // 0..56
            const float sc = inv[m];
            uint4 p;
            p.x = (unsigned)f2bf(tile[d8 + 0][m] * sc) | ((unsigned)f2bf(tile[d8 + 1][m] * sc) << 16);
            p.y = (unsigned)f2bf(tile[d8 + 2][m] * sc) | ((unsigned)f2bf(tile[d8 + 3][m] * sc) << 16);
            p.z = (unsigned)f2bf(tile[d8 + 4][m] * sc) | ((unsigned)f2bf(tile[d8 + 5][m] * sc) << 16);
            p.w = (unsigned)f2bf(tile[d8 + 6][m] * sc) | ((unsigned)f2bf(tile[d8 + 7][m] * sc) << 16);
            *reinterpret_cast<uint4*>(&ant[(size_t)(mB + m) * D_DIM + dB + d8]) = p;
        }
    }
}

// ---------- K2: fused bf16-MFMA GEMM + CF statistic ----------
// 256 thr (4 waves: 2 b-row halves x 2 m-col halves), tile 128 b x 32 m, K=512, BK=64.
// CF state = 16 NAMED f32x2 regs (rule #20: arrays with non-unrolled index -> scratch).
#define CHEB(CS) { const f32x2 nxt = c2 * cur - prev; prev = cur; cur = nxt; CS += cur; }
#define CF_ALL(V) { \
    float s1, c1; fast_sincos((V) * DT, s1, c1); \
    const float c2 = 2.0f * c1; \
    f32x2 prev = {1.0f, 0.0f}; \
    f32x2 cur  = {c1, s1}; \
    cs0 += cur; \
    CHEB(cs1)  CHEB(cs2)  CHEB(cs3)  CHEB(cs4)  CHEB(cs5) \
    CHEB(cs6)  CHEB(cs7)  CHEB(cs8)  CHEB(cs9)  CHEB(cs10) \
    CHEB(cs11) CHEB(cs12) CHEB(cs13) CHEB(cs14) CHEB(cs15) }
#define RED(CS) { \
    CS.x += __shfl_xor(CS.x, 16); CS.x += __shfl_xor(CS.x, 32); \
    CS.y += __shfl_xor(CS.y, 16); CS.y += __shfl_xor(CS.y, 32); }
#define ST(CS, K) { wred[wc][l15][K] = CS.x; wred[wc][l15][16 + K] = CS.y; }
#define FIN(CS, KK) { \
    constexpr float tk = DT * (float)(KK); \
    const float g  = __expf(-0.5f * tk * tk); \
    const float w  = (((KK) == 16) ? DT : 2.0f * DT) * g; \
    const float totC = wred[wc][l15][(KK) - 1]      + CS.x; \
    const float totS = wred[wc][l15][16 + (KK) - 1] + CS.y; \
    const float cm = fmaf(totC, invB, -g); \
    const float sm = totS * invB; \
    s = fmaf(w, fmaf(cm, cm, sm * sm), s); }

__global__ __launch_bounds__(256, 4) void fused_kernel(const ushort* __restrict__ zb,
                                                       const ushort* __restrict__ ant,
                                                       float* __restrict__ partials) {
    __shared__ __align__(16) ushort As[128][72];    // +16B pad per row
    __shared__ __align__(16) ushort Bs[32][72];
    __shared__ float wred[2][16][33];               // [wc][col][k | 16+k], padded
    __shared__ float bred[2];

    const int tid  = threadIdx.x;
    const int mB   = blockIdx.x * 32;               // 32 m-blocks share one zb t-slice
    const int t    = blockIdx.y;                    // 0..31
    const int wave = tid >> 6;
    const int lane = tid & 63;
    const int wr   = wave >> 1;                     // b-row half
    const int wc   = wave & 1;                      // m-col half
    const int l15  = lane & 15;
    const int lhi  = lane >> 4;

    const ushort* zrow = zb + (size_t)t * B_DIM * D_DIM;

    const int ar0 = tid >> 3;            // A rows tid/8 + 32q
    const int ac  = (tid & 7) * 8;
    const int br0 = tid >> 3;            // B rows 0..31
    const int bc  = (tid & 7) * 8;

    f32x4 acc[4];
#pragma unroll
    for (int fm = 0; fm < 4; ++fm) acc[fm] = (f32x4)(0.0f);

    uint4 aReg[4], bReg;
#pragma unroll
    for (int q = 0; q < 4; ++q)
        aReg[q] = *reinterpret_cast<const uint4*>(&zrow[(size_t)(ar0 + 32 * q) * D_DIM + ac]);
    bReg = *reinterpret_cast<const uint4*>(&ant[(size_t)(mB + br0) * D_DIM + bc]);

#pragma unroll
    for (int it = 0; it < 8; ++it) {
        __syncthreads();
#pragma unroll
        for (int q = 0; q < 4; ++q)
            *reinterpret_cast<uint4*>(&As[ar0 + 32 * q][ac]) = aReg[q];
        *reinterpret_cast<uint4*>(&Bs[br0][bc]) = bReg;
        __syncthreads();

        if (it < 7) {                               // prefetch next K-tile
            const int k0 = (it + 1) * 64;
#pragma unroll
            for (int q = 0; q < 4; ++q)
                aReg[q] = *reinterpret_cast<const uint4*>(&zrow[(size_t)(ar0 + 32 * q) * D_DIM + k0 + ac]);
            bReg = *reinterpret_cast<const uint4*>(&ant[(size_t)(mB + br0) * D_DIM + k0 + bc]);
        }

#pragma unroll
        for (int ks = 0; ks < 2; ++ks) {
            const bf16x8 bfrag = *reinterpret_cast<const bf16x8*>(&Bs[wc * 16 + l15][ks * 32 + lhi * 8]);
#pragma unroll
            for (int fm = 0; fm < 4; ++fm) {
                const bf16x8 afrag = *reinterpret_cast<const bf16x8*>(&As[wr * 64 + fm * 16 + l15][ks * 32 + lhi * 8]);
                acc[fm] = __builtin_amdgcn_mfma_f32_16x16x32_bf16(afrag, bfrag, acc[fm], 0, 0, 0);
            }
        }
    }

    // ---- CF accumulation into 16 NAMED f32x2 registers ----
    f32x2 cs0  = {0.f, 0.f}, cs1  = {0.f, 0.f}, cs2  = {0.f, 0.f}, cs3  = {0.f, 0.f};
    f32x2 cs4  = {0.f, 0.f}, cs5  = {0.f, 0.f}, cs6  = {0.f, 0.f}, cs7  = {0.f, 0.f};
    f32x2 cs8  = {0.f, 0.f}, cs9  = {0.f, 0.f}, cs10 = {0.f, 0.f}, cs11 = {0.f, 0.f};
    f32x2 cs12 = {0.f, 0.f}, cs13 = {0.f, 0.f}, cs14 = {0.f, 0.f}, cs15 = {0.f, 0.f};

#pragma unroll
    for (int fm = 0; fm < 4; ++fm) {
        const f32x4 av = acc[fm];
        CF_ALL(av.x) CF_ALL(av.y) CF_ALL(av.z) CF_ALL(av.w)
    }

    // reduce over the wave's 64 b-rows (4 lane-groups)
    RED(cs0)  RED(cs1)  RED(cs2)  RED(cs3)  RED(cs4)  RED(cs5)  RED(cs6)  RED(cs7)
    RED(cs8)  RED(cs9)  RED(cs10) RED(cs11) RED(cs12) RED(cs13) RED(cs14) RED(cs15)

    if (wr == 0 && lane < 16) {
        ST(cs0, 0)   ST(cs1, 1)   ST(cs2, 2)   ST(cs3, 3)
        ST(cs4, 4)   ST(cs5, 5)   ST(cs6, 6)   ST(cs7, 7)
        ST(cs8, 8)   ST(cs9, 9)   ST(cs10, 10) ST(cs11, 11)
        ST(cs12, 12) ST(cs13, 13) ST(cs14, 14) ST(cs15, 15)
    }
    __syncthreads();

    if (wr == 1) {
        const float invB = 1.0f / 128.0f;
        float s = 0.0f;
        FIN(cs0, 1)   FIN(cs1, 2)   FIN(cs2, 3)   FIN(cs3, 4)
        FIN(cs4, 5)   FIN(cs5, 6)   FIN(cs6, 7)   FIN(cs7, 8)
        FIN(cs8, 9)   FIN(cs9, 10)  FIN(cs10, 11) FIN(cs11, 12)
        FIN(cs12, 13) FIN(cs13, 14) FIN(cs14, 15) FIN(cs15, 16)
        // butterfly over all 64 lanes: each col counted 4x (lhi copies)
#pragma unroll
        for (int m = 1; m < 64; m <<= 1) s += __shfl_xor(s, m);
        if (lane == 0) bred[wc] = s;
    }
    __syncthreads();
    if (tid == 0)
        partials[blockIdx.y * 32 + blockIdx.x] = (bred[0] + bred[1]) * 0.25f * 128.0f;
}

// ---------- K3: final reduce of 1024 partials ----------
__global__ __launch_bounds__(256) void finalize_kernel(const float* __restrict__ partials,
                                                       float* __restrict__ out) {
    __shared__ float red[256];
    const int tid = threadIdx.x;
    red[tid] = partials[tid] + partials[tid + 256] + partials[tid + 512] + partials[tid + 768];
    __syncthreads();
    for (int s = 128; s > 0; s >>= 1) {
        if (tid < s) red[tid] += red[tid + s];
        __syncthreads();
    }
    if (tid == 0) out[0] = red[0] * (1.0f / (float)(T_DIM * M_DIM));
}

extern "C" void kernel_launch(void* const* d_in, const int* in_sizes, int n_in,
                              void* d_out, int out_size, void* d_ws, size_t ws_size,
                              hipStream_t stream) {
    const float* z = (const float*)d_in[0];   // (32,128,512)
    const float* A = (const float*)d_in[1];   // (512,1024)
    float* out = (float*)d_out;

    ushort* zb       = (ushort*)d_ws;                                   // 4 MB
    ushort* ant      = (ushort*)((char*)d_ws + (size_t)T_DIM * B_DIM * D_DIM * 2); // 1 MB
    float*  partials = (float*)((char*)d_ws + (size_t)T_DIM * B_DIM * D_DIM * 2
                                            + (size_t)M_DIM * D_DIM * 2);          // 4 KB

    prep_kernel<<<16 + 1024, 256, 0, stream>>>(A, z, zb, ant);
    fused_kernel<<<dim3(M_DIM / 32, T_DIM), 256, 0, stream>>>(zb, ant, partials);
    finalize_kernel<<<1, 256, 0, stream>>>(partials, out);
}

// Round 6
// 53.925 us; speedup vs baseline: 1.1670x; 1.1670x over previous
//
#include <hip/hip_runtime.h>
#include <hip/hip_bf16.h>
#include <math.h>

#define T_DIM 32
#define B_DIM 128
#define D_DIM 512
#define M_DIM 1024
#define R_DIM (T_DIM * B_DIM)          // 4096 proj rows

constexpr float DT = 0.1875f;          // 3.0 / 16

typedef __attribute__((ext_vector_type(8))) short bf16x8;   // 8 bf16 = 4 VGPR
typedef __attribute__((ext_vector_type(4))) float f32x4;    // MFMA acc
typedef __attribute__((ext_vector_type(2))) float f32x2;    // packed (cos,sin)

__device__ __forceinline__ ushort f2bf(float f) {           // RNE fp32->bf16
    unsigned u = __float_as_uint(f);
    u += 0x7FFFu + ((u >> 16) & 1u);
    return (ushort)(u >> 16);
}

// v_sin/v_cos take REVOLUTIONS (ISA: D=sin(S0*2pi)); reduce with floor.
__device__ __forceinline__ void fast_sincos(float theta, float& s, float& c) {
    constexpr float INV_2PI = 0.15915494309189535f;
    float r = theta * INV_2PI;
    r -= floorf(r);
    s = __builtin_amdgcn_sinf(r);
    c = __builtin_amdgcn_cosf(r);
}

// ---------- K1: column inverse norms of A ----------
__global__ __launch_bounds__(256) void colnorm_kernel(const float* __restrict__ A,
                                                      float* __restrict__ invn) {
    __shared__ float red[256];
    const int mB = blockIdx.x * 16;
    const int mo = threadIdx.x & 15;
    const int dg = threadIdx.x >> 4;
    float ss = 0.0f;
#pragma unroll 4
    for (int i = 0; i < 32; ++i) {
        float v = A[(size_t)(dg * 32 + i) * M_DIM + mB + mo];
        ss = fmaf(v, v, ss);
    }
    red[threadIdx.x] = ss;
    __syncthreads();
    for (int s = 128; s >= 16; s >>= 1) {
        if (threadIdx.x < s) red[threadIdx.x] += red[threadIdx.x + s];
        __syncthreads();
    }
    if (threadIdx.x < 16)
        invn[mB + mo] = 1.0f / fmaxf(sqrtf(red[threadIdx.x]), 1e-12f);
}

// ---------- K2: z fp32 -> bf16 ----------
__global__ __launch_bounds__(256) void zconv_kernel(const float* __restrict__ z,
                                                    ushort* __restrict__ zb) {
    const size_t i = ((size_t)blockIdx.x * 256 + threadIdx.x) * 8;
    const float4 a = *reinterpret_cast<const float4*>(&z[i]);
    const float4 b = *reinterpret_cast<const float4*>(&z[i + 4]);
    uint4 p;
    p.x = (unsigned)f2bf(a.x) | ((unsigned)f2bf(a.y) << 16);
    p.y = (unsigned)f2bf(a.z) | ((unsigned)f2bf(a.w) << 16);
    p.z = (unsigned)f2bf(b.x) | ((unsigned)f2bf(b.y) << 16);
    p.w = (unsigned)f2bf(b.z) | ((unsigned)f2bf(b.w) << 16);
    *reinterpret_cast<uint4*>(&zb[i]) = p;
}

// ---------- K3: Ant[m][d] = A[d][m] * invn[m] (bf16) ----------
__global__ __launch_bounds__(256) void atrans_kernel(const float* __restrict__ A,
                                                     const float* __restrict__ invn,
                                                     ushort* __restrict__ ant) {
    __shared__ float tile[64][65];
    const int dB = blockIdx.x * 64;
    const int mB = blockIdx.y * 64;
#pragma unroll
    for (int it = 0; it < 4; ++it) {
        const int r = it * 16 + (threadIdx.x >> 4);
        const int c = (threadIdx.x & 15) * 4;
        const float4 v = *reinterpret_cast<const float4*>(&A[(size_t)(dB + r) * M_DIM + mB + c]);
        tile[r][c] = v.x; tile[r][c + 1] = v.y; tile[r][c + 2] = v.z; tile[r][c + 3] = v.w;
    }
    __syncthreads();
#pragma unroll
    for (int it = 0; it < 2; ++it) {
        const int ci = it * 256 + threadIdx.x;
        const int m  = ci >> 3;
        const int d8 = (ci & 7) * 8;
        const float sc = invn[mB + m];
        uint4 p;
        p.x = (unsigned)f2bf(tile[d8 + 0][m] * sc) | ((unsigned)f2bf(tile[d8 + 1][m] * sc) << 16);
        p.y = (unsigned)f2bf(tile[d8 + 2][m] * sc) | ((unsigned)f2bf(tile[d8 + 3][m] * sc) << 16);
        p.z = (unsigned)f2bf(tile[d8 + 4][m] * sc) | ((unsigned)f2bf(tile[d8 + 5][m] * sc) << 16);
        p.w = (unsigned)f2bf(tile[d8 + 6][m] * sc) | ((unsigned)f2bf(tile[d8 + 7][m] * sc) << 16);
        *reinterpret_cast<uint4*>(&ant[(size_t)(mB + m) * D_DIM + dB + d8]) = p;
    }
}

// ---------- K4: bf16 MFMA GEMM -> proj_cm (COLUMN-major [M][R], bf16) ----------
// 128x128 tile, 4 waves 2x2, 4x4 frags of 16x16x32, BK=32, reg-staged LDS.
__global__ __launch_bounds__(256) void gemm_kernel(const ushort* __restrict__ zb,
                                                   const ushort* __restrict__ ant,
                                                   ushort* __restrict__ proj_cm) {
    __shared__ __align__(16) ushort As[128][32];
    __shared__ __align__(16) ushort Bs[128][32];

    const int tid    = threadIdx.x;
    const int colBlk = blockIdx.x * 128;   // 8  (fast dim: share zb slice in L2)
    const int rowBlk = blockIdx.y * 128;   // 32 (= t)
    const int wave = tid >> 6;
    const int lane = tid & 63;
    const int wr   = wave >> 1;
    const int wc   = wave & 1;
    const int l15  = lane & 15;
    const int lhi  = lane >> 4;

    // staging map: idx = c*256+tid in 0..511 -> row = idx>>2, q = idx&3 (8-elem chunk)
    const int sr = tid >> 2;
    const int sq = tid & 3;

    f32x4 acc[4][4];
#pragma unroll
    for (int fm = 0; fm < 4; ++fm)
#pragma unroll
        for (int fn = 0; fn < 4; ++fn) acc[fm][fn] = (f32x4)(0.0f);

    uint4 aR[2], bR[2];
#pragma unroll
    for (int c = 0; c < 2; ++c) {
        const int r = sr + c * 64;
        aR[c] = *reinterpret_cast<const uint4*>(&zb[(size_t)(rowBlk + r) * D_DIM + sq * 8]);
        bR[c] = *reinterpret_cast<const uint4*>(&ant[(size_t)(colBlk + r) * D_DIM + sq * 8]);
    }

    for (int it = 0; it < 16; ++it) {
        __syncthreads();
#pragma unroll
        for (int c = 0; c < 2; ++c) {
            *reinterpret_cast<uint4*>(&As[sr + c * 64][sq * 8]) = aR[c];
            *reinterpret_cast<uint4*>(&Bs[sr + c * 64][sq * 8]) = bR[c];
        }
        __syncthreads();

        if (it < 15) {
            const int k0 = (it + 1) * 32;
#pragma unroll
            for (int c = 0; c < 2; ++c) {
                const int r = sr + c * 64;
                aR[c] = *reinterpret_cast<const uint4*>(&zb[(size_t)(rowBlk + r) * D_DIM + k0 + sq * 8]);
                bR[c] = *reinterpret_cast<const uint4*>(&ant[(size_t)(colBlk + r) * D_DIM + k0 + sq * 8]);
            }
        }

        bf16x8 af[4], bfr[4];
#pragma unroll
        for (int fm = 0; fm < 4; ++fm)
            af[fm] = *reinterpret_cast<const bf16x8*>(&As[wr * 64 + fm * 16 + l15][lhi * 8]);
#pragma unroll
        for (int fn = 0; fn < 4; ++fn)
            bfr[fn] = *reinterpret_cast<const bf16x8*>(&Bs[wc * 64 + fn * 16 + l15][lhi * 8]);
#pragma unroll
        for (int fm = 0; fm < 4; ++fm)
#pragma unroll
            for (int fn = 0; fn < 4; ++fn)
                acc[fm][fn] = __builtin_amdgcn_mfma_f32_16x16x32_bf16(af[fm], bfr[fn], acc[fm][fn], 0, 0, 0);
    }

    // epilogue: C/D layout col=l15 (maps to B row = m), row=lhi*4+reg (maps to A row = b).
    // proj_cm[m][row]: per (fm,fn) the lane's 4 regs are 4 consecutive rows -> ushort4.
#pragma unroll
    for (int fn = 0; fn < 4; ++fn) {
        const int m = colBlk + wc * 64 + fn * 16 + l15;
#pragma unroll
        for (int fm = 0; fm < 4; ++fm) {
            const int r0 = rowBlk + wr * 64 + fm * 16 + lhi * 4;
            ushort4 o;
            o.x = f2bf(acc[fm][fn][0]);
            o.y = f2bf(acc[fm][fn][1]);
            o.z = f2bf(acc[fm][fn][2]);
            o.w = f2bf(acc[fm][fn][3]);
            *reinterpret_cast<ushort4*>(&proj_cm[(size_t)m * R_DIM + r0]) = o;
        }
    }
}

// ---------- K5: CF statistic from proj_cm ----------
// grid (16 mchunks, 32 t), 256 thr: ml = tid&63 (m), bq = tid>>6 (32 b's each).
#define CHEB(CS) { const f32x2 nxt = c2 * cur - prev; prev = cur; cur = nxt; CS += cur; }
#define CF_ONE(U) { \
    float s1, c1; \
    fast_sincos(__uint_as_float(((unsigned)(U)) << 16) * DT, s1, c1); \
    const float c2 = 2.0f * c1; \
    f32x2 prev = {1.0f, 0.0f}; \
    f32x2 cur  = {c1, s1}; \
    cs0 += cur; \
    CHEB(cs1)  CHEB(cs2)  CHEB(cs3)  CHEB(cs4)  CHEB(cs5) \
    CHEB(cs6)  CHEB(cs7)  CHEB(cs8)  CHEB(cs9)  CHEB(cs10) \
    CHEB(cs11) CHEB(cs12) CHEB(cs13) CHEB(cs14) CHEB(cs15) }

__global__ __launch_bounds__(256) void stat_kernel(const ushort* __restrict__ proj_cm,
                                                   float* __restrict__ partials) {
    __shared__ f32x2 red4[4][64][17];     // [bq][m][k], padded (+1) for banks
    __shared__ float sred[4];

    const int tid = threadIdx.x;
    const int mB  = blockIdx.x * 64;      // 16
    const int t   = blockIdx.y;           // 32
    const int ml  = tid & 63;
    const int bq  = tid >> 6;

    const ushort* p = proj_cm + (size_t)(mB + ml) * R_DIM + t * B_DIM + bq * 32;

    f32x2 cs0  = {0.f, 0.f}, cs1  = {0.f, 0.f}, cs2  = {0.f, 0.f}, cs3  = {0.f, 0.f};
    f32x2 cs4  = {0.f, 0.f}, cs5  = {0.f, 0.f}, cs6  = {0.f, 0.f}, cs7  = {0.f, 0.f};
    f32x2 cs8  = {0.f, 0.f}, cs9  = {0.f, 0.f}, cs10 = {0.f, 0.f}, cs11 = {0.f, 0.f};
    f32x2 cs12 = {0.f, 0.f}, cs13 = {0.f, 0.f}, cs14 = {0.f, 0.f}, cs15 = {0.f, 0.f};

#pragma unroll
    for (int i = 0; i < 8; ++i) {
        const ushort4 v = *reinterpret_cast<const ushort4*>(&p[i * 4]);
        CF_ONE(v.x) CF_ONE(v.y) CF_ONE(v.z) CF_ONE(v.w)
    }

    red4[bq][ml][0]  = cs0;  red4[bq][ml][1]  = cs1;  red4[bq][ml][2]  = cs2;  red4[bq][ml][3]  = cs3;
    red4[bq][ml][4]  = cs4;  red4[bq][ml][5]  = cs5;  red4[bq][ml][6]  = cs6;  red4[bq][ml][7]  = cs7;
    red4[bq][ml][8]  = cs8;  red4[bq][ml][9]  = cs9;  red4[bq][ml][10] = cs10; red4[bq][ml][11] = cs11;
    red4[bq][ml][12] = cs12; red4[bq][ml][13] = cs13; red4[bq][ml][14] = cs14; red4[bq][ml][15] = cs15;
    __syncthreads();

    const float invB = 1.0f / 128.0f;
    float e = 0.0f;
#pragma unroll
    for (int w = 0; w < 4; ++w) {
        const int j = tid + 256 * w;      // 0..1023
        const int m = j & 63;
        const int k = j >> 6;             // 0..15
        const f32x2 s4 = red4[0][m][k] + red4[1][m][k] + red4[2][m][k] + red4[3][m][k];
        const float tk = DT * (float)(k + 1);
        const float g  = __expf(-0.5f * tk * tk);
        const float wg = ((k == 15) ? DT : 2.0f * DT) * g;
        const float cm = fmaf(s4.x, invB, -g);
        const float sm = s4.y * invB;
        e = fmaf(wg, fmaf(cm, cm, sm * sm), e);
    }

    // block scalar reduce
#pragma unroll
    for (int msk = 1; msk < 64; msk <<= 1) e += __shfl_xor(e, msk);
    if ((tid & 63) == 0) sred[tid >> 6] = e;
    __syncthreads();
    if (tid == 0)
        partials[t * 16 + blockIdx.x] = sred[0] + sred[1] + sred[2] + sred[3];
}

// ---------- K6: final reduce of 512 partials ----------
__global__ __launch_bounds__(256) void finalize_kernel(const float* __restrict__ partials,
                                                       float* __restrict__ out) {
    __shared__ float red[256];
    const int tid = threadIdx.x;
    red[tid] = partials[tid] + partials[tid + 256];
    __syncthreads();
    for (int s = 128; s > 0; s >>= 1) {
        if (tid < s) red[tid] += red[tid + s];
        __syncthreads();
    }
    // out = (1/(T*M)) * B * sum = sum / 256
    if (tid == 0) out[0] = red[0] * (1.0f / 256.0f);
}

extern "C" void kernel_launch(void* const* d_in, const int* in_sizes, int n_in,
                              void* d_out, int out_size, void* d_ws, size_t ws_size,
                              hipStream_t stream) {
    const float* z = (const float*)d_in[0];   // (32,128,512)
    const float* A = (const float*)d_in[1];   // (512,1024)
    float* out = (float*)d_out;

    char* ws = (char*)d_ws;
    ushort* zb       = (ushort*)ws;                               // 4 MB
    ushort* ant      = (ushort*)(ws + 4 * 1024 * 1024);           // 1 MB
    ushort* proj_cm  = (ushort*)(ws + 5 * 1024 * 1024);           // 8 MB
    float*  invn     = (float*)(ws + 13 * 1024 * 1024);           // 4 KB
    float*  partials = invn + M_DIM;                              // 2 KB

    colnorm_kernel<<<64, 256, 0, stream>>>(A, invn);
    zconv_kernel<<<1024, 256, 0, stream>>>(z, zb);
    atrans_kernel<<<dim3(8, 16), 256, 0, stream>>>(A, invn, ant);
    gemm_kernel<<<dim3(M_DIM / 128, R_DIM / 128), 256, 0, stream>>>(zb, ant, proj_cm);
    stat_kernel<<<dim3(16, T_DIM), 256, 0, stream>>>(proj_cm, partials);
    finalize_kernel<<<1, 256, 0, stream>>>(partials, out);
}